// Round 28
// baseline (421.386 us; speedup 1.0000x reference)
//
#include <hip/hip_runtime.h>
#include <hip/hip_bf16.h>
#include <math.h>
#include <stdint.h>

#define BB 4
#define SS 4096
#define DD 128
#define KK 32
#define QB 8
#define CB2 128
#define NC 64
#define FINF __builtin_inff()

typedef __attribute__((ext_vector_type(8))) short short8v;
typedef __attribute__((ext_vector_type(4))) float f32x4;

__device__ __forceinline__ unsigned short f2bf(float x) {
    __hip_bfloat16 h = __float2bfloat16(x);
    return *reinterpret_cast<unsigned short*>(&h);
}

__device__ __forceinline__ void gload16(const void* gsrc, void* ldsdst) {
    __builtin_amdgcn_global_load_lds(
        (const __attribute__((address_space(1))) unsigned int*)gsrc,
        (__attribute__((address_space(3))) unsigned int*)ldsdst, 16, 0, 0);
}

// ---------- prep: exact sq (proven) + bf16 pre-swizzled copy of emb ----------
__global__ __launch_bounds__(256)
void prep_kernel(const float* __restrict__ emb, float* __restrict__ sqg,
                 unsigned short* __restrict__ ebf) {
    const int t    = threadIdx.x;
    const int lane = t & 63;
    const int wid  = t >> 6;
    const int grp  = lane >> 4;
    const int gl   = lane & 15;
    const int row  = blockIdx.x * 16 + wid * 4 + grp;
    const float* rp = emb + (size_t)row * DD;

    const float p0 = rp[  0 + gl], p1 = rp[ 16 + gl], p2 = rp[ 32 + gl], p3 = rp[ 48 + gl];
    const float p4 = rp[ 64 + gl], p5 = rp[ 80 + gl], p6 = rp[ 96 + gl], p7 = rp[112 + gl];
    const float t0 = __fmul_rn(p0, p0), t1 = __fmul_rn(p1, p1);
    const float t2 = __fmul_rn(p2, p2), t3 = __fmul_rn(p3, p3);
    const float t4 = __fmul_rn(p4, p4), t5 = __fmul_rn(p5, p5);
    const float t6 = __fmul_rn(p6, p6), t7 = __fmul_rn(p7, p7);
    const float s = __fadd_rn(__fadd_rn(__fadd_rn(t0, t1), __fadd_rn(t2, t3)),
                              __fadd_rn(__fadd_rn(t4, t5), __fadd_rn(t6, t7)));
    const int gbase = lane & 48;
    const float u = __fadd_rn(s, __shfl(s, gbase + ((lane & 15) + 8)));
    const float w = __fadd_rn(u, __shfl(u, gbase + ((lane & 15) + 4)));
    const float w0 = __shfl(w, gbase + 0), w1 = __shfl(w, gbase + 1);
    const float w2 = __shfl(w, gbase + 2), w3 = __shfl(w, gbase + 3);
    if (gl == 0) sqg[row] = __fadd_rn(__fadd_rn(w0, w2), __fadd_rn(w1, w3));

    const float4 va = *(const float4*)(rp + gl * 8);
    const float4 vb = *(const float4*)(rp + gl * 8 + 4);
    short8v pk;
    pk[0] = (short)f2bf(va.x); pk[1] = (short)f2bf(va.y);
    pk[2] = (short)f2bf(va.z); pk[3] = (short)f2bf(va.w);
    pk[4] = (short)f2bf(vb.x); pk[5] = (short)f2bf(vb.y);
    pk[6] = (short)f2bf(vb.z); pk[7] = (short)f2bf(vb.w);
    const int gsw = gl ^ (row & 7);
    *(short8v*)&ebf[(size_t)row * 128 + gsw * 8] = pk;
}

// ---------- fast main: 1 row/wave, bitonic tile-0 init, batched insertion ----------
__global__ __launch_bounds__(512, 6)
void knn_fast3_kernel(const float* __restrict__ emb, const float* __restrict__ sqg,
                      const unsigned short* __restrict__ ebf, float* __restrict__ out) {
    __shared__ unsigned short qsb[16][128];    // 4 KB (rows 8-15 zeroed)
    __shared__ unsigned short csb[CB2][128];   // 32 KB
    __shared__ float qsf[QB][128];             // 4 KB
    __shared__ float keybuf[QB][CB2];          // 4 KB
    __shared__ float sqq_s[QB];

    const int t    = threadIdx.x;
    const int lane = t & 63;
    const int wave = t >> 6;
    const int bx   = blockIdx.x;
    const int b    = bx >> 9;
    const int rb   = bx & 511;
    const int R0   = rb * QB;
    const float* embb = emb + (size_t)b * SS * DD;
    const float* sqb  = sqg + (size_t)b * SS;
    const unsigned short* ebfb = ebf + (size_t)b * SS * 128;

    // zero qsb rows 8..15 (2 KB = 512 u32)
    ((unsigned*)&qsb[8][0])[t] = 0u;
    // stage q rows 0..7: bf16 via gload_lds (waves 0,1), f32 via normal loads
    if (wave < 2)
        gload16((const char*)ebfb + (size_t)R0 * 256 + wave * 1024 + lane * 16,
                (char*)&qsb[0][0] + wave * 1024);
    if (t < QB * 32) {
        const int r = t >> 5, c4 = t & 31;
        *(float4*)&qsf[r][c4 * 4] = *(const float4*)(embb + (size_t)(R0 + r) * DD + c4 * 4);
    }
    if (t < QB) sqq_s[t] = sqb[R0 + t];

    float dl = FINF;
    int   il = 0;
    float tau = FINF;

    const int arow = lane & 15;
    const int bcol = wave * 16 + (lane & 15);

    // preload tile 0 (32 KB: 8 waves x 4 gload16)
    #pragma unroll
    for (int c2 = 0; c2 < 4; ++c2)
        gload16((const char*)ebfb + (wave * 4 + c2) * 1024 + lane * 16,
                (char*)&csb[0][0] + (wave * 4 + c2) * 1024);
    __syncthreads();

    for (int tile = 0; tile < SS / CB2; ++tile) {
        const int j0 = tile * CB2;

        // phase B: MFMA gram + approx d2 keys (rows 0..7 only)
        f32x4 acc = {0.f, 0.f, 0.f, 0.f};
        #pragma unroll
        for (int ks = 0; ks < 4; ++ks) {
            const int kg = ks * 4 + (lane >> 4);
            short8v a  = *(const short8v*)&qsb[arow][(kg ^ (arow & 7)) << 3];
            short8v bf = *(const short8v*)&csb[bcol][(kg ^ (bcol & 7)) << 3];
            acc = __builtin_amdgcn_mfma_f32_16x16x32_bf16(a, bf, acc, 0, 0, 0);
        }
        {
            const float sqcv = sqb[j0 + bcol];
            const int grow_base = (lane >> 4) * 4;
            #pragma unroll
            for (int q = 0; q < 4; ++q) {
                const int grow = grow_base + q;
                if (grow < QB) {
                    float d2v = sqq_s[grow] + sqcv - 2.0f * acc[q];
                    if (R0 + grow == j0 + bcol) d2v = FINF;
                    keybuf[grow][bcol] = d2v;
                }
            }
        }
        __syncthreads();   // (1) csb consumed, keybuf ready

        // prefetch next tile into csb (overlaps with phase C)
        if (tile + 1 < SS / CB2) {
            const size_t base = (size_t)(j0 + CB2) * 256;
            #pragma unroll
            for (int c2 = 0; c2 < 4; ++c2)
                gload16((const char*)ebfb + base + (wave * 4 + c2) * 1024 + lane * 16,
                        (char*)&csb[0][0] + (wave * 4 + c2) * 1024);
        }

        // phase C: wave owns row = wave
        const int r = wave;
        const float v0 = keybuf[r][lane];
        const float v1 = keybuf[r][64 + lane];

        if (tile == 0) {
            // bitonic-64 ascending sort of cols 0..63 (packed keybits<<32 | idx)
            unsigned long long pk =
                ((unsigned long long)__float_as_uint(v0) << 32) | (unsigned)(j0 + lane);
            #pragma unroll
            for (int k = 2; k <= 64; k <<= 1) {
                #pragma unroll
                for (int j = k >> 1; j > 0; j >>= 1) {
                    const unsigned long long other = __shfl_xor(pk, j);
                    const bool up = ((lane & k) == 0);
                    const bool lower = ((lane & j) == 0);
                    const bool keepmin = (lower == up);
                    const bool otherSmaller = other < pk;
                    pk = (keepmin == otherSmaller) ? other : pk;
                }
            }
            dl = __uint_as_float((unsigned)(pk >> 32));
            il = (int)(unsigned)(pk & 0xffffffffu);
            tau = __shfl(dl, NC - 1);
            // cols 64..127 via batched insertion
            unsigned long long pend1 = __ballot(v1 < tau);
            while (pend1) {
                const int s = __ffsll(pend1) - 1;
                pend1 &= pend1 - 1;
                const float vs = __shfl(v1, s);
                const int js = j0 + 64 + s;
                const float pd = __shfl_up(dl, 1);
                const int   pi = __shfl_up(il, 1);
                const unsigned long long m = __ballot(dl <= vs);
                const int p = __popcll(m);
                if (lane == p)      { dl = vs; il = js; }
                else if (lane > p)  { dl = pd; il = pi; }
            }
            tau = __shfl(dl, NC - 1);
        } else {
            unsigned long long pend0 = __ballot(v0 < tau);
            unsigned long long pend1 = __ballot(v1 < tau);
            while (pend0) {
                const int s = __ffsll(pend0) - 1;
                pend0 &= pend0 - 1;
                const float vs = __shfl(v0, s);
                const int js = j0 + s;
                const float pd = __shfl_up(dl, 1);
                const int   pi = __shfl_up(il, 1);
                const unsigned long long m = __ballot(dl <= vs);
                const int p = __popcll(m);
                if (lane == p)      { dl = vs; il = js; }
                else if (lane > p)  { dl = pd; il = pi; }
            }
            while (pend1) {
                const int s = __ffsll(pend1) - 1;
                pend1 &= pend1 - 1;
                const float vs = __shfl(v1, s);
                const int js = j0 + 64 + s;
                const float pd = __shfl_up(dl, 1);
                const int   pi = __shfl_up(il, 1);
                const unsigned long long m = __ballot(dl <= vs);
                const int p = __popcll(m);
                if (lane == p)      { dl = vs; il = js; }
                else if (lane > p)  { dl = pd; il = pi; }
            }
            tau = __shfl(dl, NC - 1);
        }
        __syncthreads();   // (2) keybuf consumed; drains vmcnt -> csb ready
    }

    // exact phase: golden-exact keys for the 64 candidates (bit-exact)
    {
        const int r  = wave;
        const int gi = R0 + r;
        const int ce = il;
        const float* cp = embb + (size_t)ce * DD;
        float g = 0.f;
        #pragma unroll 8
        for (int k4 = 0; k4 < 32; ++k4) {
            const float4 qv = *(const float4*)&qsf[r][k4 * 4];
            const float4 cv = *(const float4*)(cp + k4 * 4);
            g = fmaf(qv.x, cv.x, g);
            g = fmaf(qv.y, cv.y, g);
            g = fmaf(qv.z, cv.z, g);
            g = fmaf(qv.w, cv.w, g);
        }
        const float tsum = __fadd_rn(sqq_s[r], sqb[ce]);
        float d2v = __fsub_rn(tsum, __fmul_rn(2.0f, g));
        d2v = fmaxf(d2v, 0.0f);
        const float ke = (float)sqrt((double)d2v);
        int rank = 0;
        for (int c = 0; c < NC; ++c) {
            const float kc = __shfl(ke, c);
            const int   jc = __shfl(ce, c);
            rank += (kc < ke) || (kc == ke && jc < ce);
        }
        if (rank < KK) {
            const size_t o = ((size_t)b * SS + gi) * KK + rank;
            out[o] = (float)ce;
            out[(size_t)BB * SS * KK + o] = ke;
        }
    }
}

extern "C" void kernel_launch(void* const* d_in, const int* in_sizes, int n_in,
                              void* d_out, int out_size, void* d_ws, size_t ws_size,
                              hipStream_t stream) {
    const float* emb = (const float*)d_in[0];
    float* out = (float*)d_out;
    float* sqg = (float*)d_ws;
    (void)in_sizes; (void)n_in; (void)out_size; (void)ws_size;
    unsigned short* ebf = (unsigned short*)((char*)d_ws + 65536);
    prep_kernel<<<dim3(BB * SS / 16), dim3(256), 0, stream>>>(emb, sqg, ebf);
    knn_fast3_kernel<<<dim3(BB * (SS / QB)), dim3(512), 0, stream>>>(emb, sqg, ebf, out);
}

// Round 29
// 354.294 us; speedup vs baseline: 1.1894x; 1.1894x over previous
//
#include <hip/hip_runtime.h>
#include <hip/hip_bf16.h>
#include <math.h>
#include <stdint.h>

#define BB 4
#define SS 4096
#define DD 128
#define KK 32
#define QB 16
#define CB2 128
#define NC 64
#define FINF __builtin_inff()

typedef __attribute__((ext_vector_type(8))) short short8v;
typedef __attribute__((ext_vector_type(4))) float f32x4;

__device__ __forceinline__ unsigned short f2bf(float x) {
    __hip_bfloat16 h = __float2bfloat16(x);
    return *reinterpret_cast<unsigned short*>(&h);
}

__device__ __forceinline__ void gload16(const void* gsrc, void* ldsdst) {
    __builtin_amdgcn_global_load_lds(
        (const __attribute__((address_space(1))) unsigned int*)gsrc,
        (__attribute__((address_space(3))) unsigned int*)ldsdst, 16, 0, 0);
}

// ---------- prep: exact sq (proven) + bf16 pre-swizzled copy of emb ----------
__global__ __launch_bounds__(256)
void prep_kernel(const float* __restrict__ emb, float* __restrict__ sqg,
                 unsigned short* __restrict__ ebf) {
    const int t    = threadIdx.x;
    const int lane = t & 63;
    const int wid  = t >> 6;
    const int grp  = lane >> 4;
    const int gl   = lane & 15;
    const int row  = blockIdx.x * 16 + wid * 4 + grp;
    const float* rp = emb + (size_t)row * DD;

    const float p0 = rp[  0 + gl], p1 = rp[ 16 + gl], p2 = rp[ 32 + gl], p3 = rp[ 48 + gl];
    const float p4 = rp[ 64 + gl], p5 = rp[ 80 + gl], p6 = rp[ 96 + gl], p7 = rp[112 + gl];
    const float t0 = __fmul_rn(p0, p0), t1 = __fmul_rn(p1, p1);
    const float t2 = __fmul_rn(p2, p2), t3 = __fmul_rn(p3, p3);
    const float t4 = __fmul_rn(p4, p4), t5 = __fmul_rn(p5, p5);
    const float t6 = __fmul_rn(p6, p6), t7 = __fmul_rn(p7, p7);
    const float s = __fadd_rn(__fadd_rn(__fadd_rn(t0, t1), __fadd_rn(t2, t3)),
                              __fadd_rn(__fadd_rn(t4, t5), __fadd_rn(t6, t7)));
    const int gbase = lane & 48;
    const float u = __fadd_rn(s, __shfl(s, gbase + ((lane & 15) + 8)));
    const float w = __fadd_rn(u, __shfl(u, gbase + ((lane & 15) + 4)));
    const float w0 = __shfl(w, gbase + 0), w1 = __shfl(w, gbase + 1);
    const float w2 = __shfl(w, gbase + 2), w3 = __shfl(w, gbase + 3);
    if (gl == 0) sqg[row] = __fadd_rn(__fadd_rn(w0, w2), __fadd_rn(w1, w3));

    const float4 va = *(const float4*)(rp + gl * 8);
    const float4 vb = *(const float4*)(rp + gl * 8 + 4);
    short8v pk;
    pk[0] = (short)f2bf(va.x); pk[1] = (short)f2bf(va.y);
    pk[2] = (short)f2bf(va.z); pk[3] = (short)f2bf(va.w);
    pk[4] = (short)f2bf(vb.x); pk[5] = (short)f2bf(vb.y);
    pk[6] = (short)f2bf(vb.z); pk[7] = (short)f2bf(vb.w);
    const int gsw = gl ^ (row & 7);
    *(short8v*)&ebf[(size_t)row * 128 + gsw * 8] = pk;
}

// ---------- fast main: 16 waves, 1 row/wave insertion, waves 0-7 do MFMA ----------
__global__ __launch_bounds__(1024, 8)
void knn_fast4_kernel(const float* __restrict__ emb, const float* __restrict__ sqg,
                      const unsigned short* __restrict__ ebf, float* __restrict__ out) {
    __shared__ unsigned short qsb[QB][128];    // 4 KB
    __shared__ unsigned short csb[CB2][128];   // 32 KB
    __shared__ float qsf[QB][128];             // 8 KB
    __shared__ float keybuf[QB][CB2];          // 8 KB
    __shared__ float sqq_s[QB];

    const int t    = threadIdx.x;
    const int lane = t & 63;
    const int wave = t >> 6;
    const int bx   = blockIdx.x;
    const int b    = bx >> 8;
    const int rb   = bx & 255;
    const int R0   = rb * QB;
    const float* embb = emb + (size_t)b * SS * DD;
    const float* sqb  = sqg + (size_t)b * SS;
    const unsigned short* ebfb = ebf + (size_t)b * SS * 128;

    // stage q: bf16 via gload_lds (waves 0-3), f32 via normal loads (t<512)
    if (wave < 4)
        gload16((const char*)ebfb + (size_t)R0 * 256 + wave * 1024 + lane * 16,
                (char*)&qsb[0][0] + wave * 1024);
    if (t < QB * 32) {
        const int r = t >> 5, c4 = t & 31;
        *(float4*)&qsf[r][c4 * 4] = *(const float4*)(embb + (size_t)(R0 + r) * DD + c4 * 4);
    }
    if (t < QB) sqq_s[t] = sqb[R0 + t];

    float dl = FINF;
    int   il = 0;
    float tau = FINF;

    const int arow = lane & 15;
    const int bcol = (wave & 7) * 16 + (lane & 15);

    // preload tile 0 (32 KB: 16 waves x 2 gload16)
    #pragma unroll
    for (int c2 = 0; c2 < 2; ++c2)
        gload16((const char*)ebfb + (wave * 2 + c2) * 1024 + lane * 16,
                (char*)&csb[0][0] + (wave * 2 + c2) * 1024);
    __syncthreads();

    for (int tile = 0; tile < SS / CB2; ++tile) {
        const int j0 = tile * CB2;

        // phase B: MFMA gram + approx d2 keys (waves 0-7 only; 16x16 covers all QB rows)
        if (wave < 8) {
            f32x4 acc = {0.f, 0.f, 0.f, 0.f};
            #pragma unroll
            for (int ks = 0; ks < 4; ++ks) {
                const int kg = ks * 4 + (lane >> 4);
                short8v a  = *(const short8v*)&qsb[arow][(kg ^ (arow & 7)) << 3];
                short8v bf = *(const short8v*)&csb[bcol][(kg ^ (bcol & 7)) << 3];
                acc = __builtin_amdgcn_mfma_f32_16x16x32_bf16(a, bf, acc, 0, 0, 0);
            }
            const float sqcv = sqb[j0 + bcol];
            const int grow_base = (lane >> 4) * 4;
            #pragma unroll
            for (int q = 0; q < 4; ++q) {
                const int grow = grow_base + q;
                float d2v = sqq_s[grow] + sqcv - 2.0f * acc[q];
                if (R0 + grow == j0 + bcol) d2v = FINF;
                keybuf[grow][bcol] = d2v;
            }
        }
        __syncthreads();   // (1) csb consumed, keybuf ready

        // prefetch next tile into csb (overlaps with phase C)
        if (tile + 1 < SS / CB2) {
            const size_t base = (size_t)(j0 + CB2) * 256;
            #pragma unroll
            for (int c2 = 0; c2 < 2; ++c2)
                gload16((const char*)ebfb + base + (wave * 2 + c2) * 1024 + lane * 16,
                        (char*)&csb[0][0] + (wave * 2 + c2) * 1024);
        }

        // phase C: wave w owns row w
        const int r = wave;
        const float v0 = keybuf[r][lane];
        const float v1 = keybuf[r][64 + lane];

        if (tile == 0) {
            // bitonic-64 ascending sort of cols 0..63 (packed keybits<<32 | idx)
            unsigned long long pk =
                ((unsigned long long)__float_as_uint(v0) << 32) | (unsigned)(j0 + lane);
            #pragma unroll
            for (int k = 2; k <= 64; k <<= 1) {
                #pragma unroll
                for (int j = k >> 1; j > 0; j >>= 1) {
                    const unsigned long long other = __shfl_xor(pk, j);
                    const bool up = ((lane & k) == 0);
                    const bool lower = ((lane & j) == 0);
                    const bool keepmin = (lower == up);
                    const bool otherSmaller = other < pk;
                    pk = (keepmin == otherSmaller) ? other : pk;
                }
            }
            dl = __uint_as_float((unsigned)(pk >> 32));
            il = (int)(unsigned)(pk & 0xffffffffu);
            tau = __shfl(dl, NC - 1);
            unsigned long long pend1 = __ballot(v1 < tau);
            while (pend1) {
                const int s = __ffsll(pend1) - 1;
                pend1 &= pend1 - 1;
                const float vs = __shfl(v1, s);
                const int js = j0 + 64 + s;
                const float pd = __shfl_up(dl, 1);
                const int   pi = __shfl_up(il, 1);
                const unsigned long long m = __ballot(dl <= vs);
                const int p = __popcll(m);
                if (lane == p)      { dl = vs; il = js; }
                else if (lane > p)  { dl = pd; il = pi; }
            }
            tau = __shfl(dl, NC - 1);
        } else {
            unsigned long long pend0 = __ballot(v0 < tau);
            unsigned long long pend1 = __ballot(v1 < tau);
            while (pend0) {
                const int s = __ffsll(pend0) - 1;
                pend0 &= pend0 - 1;
                const float vs = __shfl(v0, s);
                const int js = j0 + s;
                const float pd = __shfl_up(dl, 1);
                const int   pi = __shfl_up(il, 1);
                const unsigned long long m = __ballot(dl <= vs);
                const int p = __popcll(m);
                if (lane == p)      { dl = vs; il = js; }
                else if (lane > p)  { dl = pd; il = pi; }
            }
            while (pend1) {
                const int s = __ffsll(pend1) - 1;
                pend1 &= pend1 - 1;
                const float vs = __shfl(v1, s);
                const int js = j0 + 64 + s;
                const float pd = __shfl_up(dl, 1);
                const int   pi = __shfl_up(il, 1);
                const unsigned long long m = __ballot(dl <= vs);
                const int p = __popcll(m);
                if (lane == p)      { dl = vs; il = js; }
                else if (lane > p)  { dl = pd; il = pi; }
            }
            tau = __shfl(dl, NC - 1);
        }
        __syncthreads();   // (2) keybuf consumed; drains vmcnt -> csb ready
    }

    // exact phase: golden-exact keys for the 64 candidates (bit-exact); 1 row/wave
    {
        const int r  = wave;
        const int gi = R0 + r;
        const int ce = il;
        const float* cp = embb + (size_t)ce * DD;
        float g = 0.f;
        #pragma unroll 8
        for (int k4 = 0; k4 < 32; ++k4) {
            const float4 qv = *(const float4*)&qsf[r][k4 * 4];
            const float4 cv = *(const float4*)(cp + k4 * 4);
            g = fmaf(qv.x, cv.x, g);
            g = fmaf(qv.y, cv.y, g);
            g = fmaf(qv.z, cv.z, g);
            g = fmaf(qv.w, cv.w, g);
        }
        const float tsum = __fadd_rn(sqq_s[r], sqb[ce]);
        float d2v = __fsub_rn(tsum, __fmul_rn(2.0f, g));
        d2v = fmaxf(d2v, 0.0f);
        const float ke = (float)sqrt((double)d2v);
        int rank = 0;
        for (int c = 0; c < NC; ++c) {
            const float kc = __shfl(ke, c);
            const int   jc = __shfl(ce, c);
            rank += (kc < ke) || (kc == ke && jc < ce);
        }
        if (rank < KK) {
            const size_t o = ((size_t)b * SS + gi) * KK + rank;
            out[o] = (float)ce;
            out[(size_t)BB * SS * KK + o] = ke;
        }
    }
}

extern "C" void kernel_launch(void* const* d_in, const int* in_sizes, int n_in,
                              void* d_out, int out_size, void* d_ws, size_t ws_size,
                              hipStream_t stream) {
    const float* emb = (const float*)d_in[0];
    float* out = (float*)d_out;
    float* sqg = (float*)d_ws;
    (void)in_sizes; (void)n_in; (void)out_size; (void)ws_size;
    unsigned short* ebf = (unsigned short*)((char*)d_ws + 65536);
    prep_kernel<<<dim3(BB * SS / 16), dim3(256), 0, stream>>>(emb, sqg, ebf);
    knn_fast4_kernel<<<dim3(BB * (SS / QB)), dim3(1024), 0, stream>>>(emb, sqg, ebf, out);
}